// Round 9
// baseline (224.441 us; speedup 1.0000x reference)
//
#include <hip/hip_runtime.h>
#include <hip/hip_bf16.h>
#include <math.h>

#define D_MODEL 1024
#define NHEADS  16
#define DK      64
#define SEQ     2048
#define BATCH   2
#define MROWS   4096   // BATCH*SEQ
#define NQT     (SEQ/64)   // 32 q-tiles

typedef unsigned short ushort_t;
using short8 = __attribute__((ext_vector_type(8))) short;
using f32x4  = __attribute__((ext_vector_type(4))) float;

__device__ __forceinline__ ushort_t f2bf(float x) {
    unsigned u = __float_as_uint(x);
    u = (u + 0x7FFFu + ((u >> 16) & 1u)) >> 16;   // RNE
    return (ushort_t)u;
}

// pack 2 floats -> 2 bf16 in one uint (v_cvt_pk_bf16_f32 on gfx950)
__device__ __forceinline__ unsigned pk2(float a, float b) {
    __hip_bfloat162 h = __float22bfloat162_rn(float2{a, b});
    unsigned u;
    __builtin_memcpy(&u, &h, 4);
    return u;
}

// async global->LDS, 16B per lane; LDS dest = wave-uniform base + lane*16
__device__ __forceinline__ void gll16(const ushort_t* g, ushort_t* l) {
    __builtin_amdgcn_global_load_lds(
        (const __attribute__((address_space(1))) void*)(g),
        (__attribute__((address_space(3))) void*)(l), 16, 0, 0);
}

// ---------------------------------------------------------------------------
// fp32 -> bf16 conversion, 7 tensors in one launch.
// ---------------------------------------------------------------------------
__global__ __launch_bounds__(256) void cvt_bf16(
    const float* s0, const float* s1, const float* s2, const float* s3,
    const float* s4, const float* s5, const float* s6,
    ushort_t* d0, ushort_t* d1, ushort_t* d2, ushort_t* d3,
    ushort_t* d4, ushort_t* d5, ushort_t* d6, int nIn, int nW)
{
    const float* s; ushort_t* d; int n;
    switch (blockIdx.y) {
        case 0: s = s0; d = d0; n = nIn; break;
        case 1: s = s1; d = d1; n = nIn; break;
        case 2: s = s2; d = d2; n = nIn; break;
        case 3: s = s3; d = d3; n = nW;  break;
        case 4: s = s4; d = d4; n = nW;  break;
        case 5: s = s5; d = d5; n = nW;  break;
        default: s = s6; d = d6; n = nW; break;
    }
    int i = (blockIdx.x * 256 + threadIdx.x) * 4;
    if (i < n) {
        float4 v = *(const float4*)&s[i];
        ushort4 o;
        o.x = f2bf(v.x); o.y = f2bf(v.y); o.z = f2bf(v.z); o.w = f2bf(v.w);
        *(ushort4*)&d[i] = o;
    }
}

// ---------------------------------------------------------------------------
// bf16 MFMA GEMM (QKV): 128x128 tile, BK=64, single-buffered gll16 (round-5
// structure: ALWAYS-swapped mfma(bf, af) for both modes — r17's SWP ternary
// broke MODE1) + r17 XCD-grouped 1-D block decode: XCD c owns 4 M-panels
// (~1MB L2-hot) while W-panels stream. Bijective:
//   c=flat&7, rr=flat>>3; t32 = c*4+(rr&3); t8 = (rr>>2)&7; z = rr>>5.
// MODE 0: C = (A @ W^T + bias)*oscale, bf16 row-major.
// MODE 1 (V^T): transposed gemm (A'=Wv channels, B'=Vb tokens);
//   epilogue emits V^T[bh][d][s] with coalesced stores.
// ---------------------------------------------------------------------------
struct GemmArgs { const ushort_t* A; const ushort_t* W; const float* bias;
                  void* C; int mode; float oscale; };

template<int MODE>
__device__ __forceinline__ void gemm_core(const GemmArgs& ga, int t32, int t8,
                                          ushort_t* As, ushort_t* Bs)
{
    const int tid  = threadIdx.x;
    const int w    = tid >> 6, lane = tid & 63;
    const int quad = lane >> 4, lx = lane & 15;
    const int mw = (w >> 1) * 64, nw = (w & 1) * 64;
    const int bm = (MODE == 1 ? t8 : t32) * 128;
    const int bn = (MODE == 1 ? t32 : t8) * 128;
    const int K = D_MODEL;

    f32x4 acc[4][4];
#pragma unroll
    for (int mt = 0; mt < 4; ++mt)
#pragma unroll
        for (int nt = 0; nt < 4; ++nt)
            acc[mt][nt] = (f32x4){0.f, 0.f, 0.f, 0.f};

    float4 b4[4];
    float  bfr[4];
#pragma unroll
    for (int i = 0; i < 4; ++i) {
        if (MODE == 0) b4[i]  = *(const float4*)&ga.bias[bn + nw + i * 16 + quad * 4];
        else           bfr[i] = ga.bias[bm + mw + i * 16 + lx];   // per-row bias
    }

    for (int k0 = 0; k0 < K; k0 += 64) {
        __syncthreads();
#pragma unroll
        for (int i = 0; i < 4; ++i) {
            int r0 = (w * 4 + i) * 8;
            int rl = r0 + (lane >> 3);
            int g  = (lane & 7) ^ (rl & 7);
            gll16(&ga.A[(size_t)(bm + rl) * K + k0 + g * 8], &As[r0 * 64]);
            gll16(&ga.W[(size_t)(bn + rl) * K + k0 + g * 8], &Bs[r0 * 64]);
        }
        __syncthreads();

#pragma unroll
        for (int ks = 0; ks < 2; ++ks) {
            short8 af[4], bf[4];
#pragma unroll
            for (int mt = 0; mt < 4; ++mt) {
                int r = mw + mt * 16 + lx;
                af[mt] = *(const short8*)&As[r * 64 + (((ks * 4 + quad) ^ (r & 7)) << 3)];
            }
#pragma unroll
            for (int nt = 0; nt < 4; ++nt) {
                int r = nw + nt * 16 + lx;
                bf[nt] = *(const short8*)&Bs[r * 64 + (((ks * 4 + quad) ^ (r & 7)) << 3)];
            }
#pragma unroll
            for (int mt = 0; mt < 4; ++mt)
#pragma unroll
                for (int nt = 0; nt < 4; ++nt)
                    acc[mt][nt] = __builtin_amdgcn_mfma_f32_16x16x32_bf16(
                        bf[nt], af[mt], acc[mt][nt], 0, 0, 0);
        }
    }

    // epilogue (swapped-call layout): lane holds row m = ..+lx (A-side),
    // 4 consecutive n per nt (B-side, quad*4).
    if (MODE == 0) {
        ushort_t* C = (ushort_t*)ga.C;
        const float os = ga.oscale;
#pragma unroll
        for (int mt = 0; mt < 4; ++mt) {
            int m = bm + mw + mt * 16 + lx;
#pragma unroll
            for (int nt = 0; nt < 4; ++nt) {
                int n0 = bn + nw + nt * 16 + quad * 4;
                uint2 u;
                u.x = pk2((acc[mt][nt][0] + b4[nt].x) * os, (acc[mt][nt][1] + b4[nt].y) * os);
                u.y = pk2((acc[mt][nt][2] + b4[nt].z) * os, (acc[mt][nt][3] + b4[nt].w) * os);
                *(uint2*)&C[(size_t)m * D_MODEL + n0] = u;
            }
        }
    } else {
        // row = channel ch (h = ch>>6, d = ch&63); col = token n0 (b, s)
        ushort_t* C = (ushort_t*)ga.C;
#pragma unroll
        for (int mt = 0; mt < 4; ++mt) {
            int ch = bm + mw + mt * 16 + lx;
            int h = ch >> 6, d = ch & 63;
            float bb = bfr[mt];
#pragma unroll
            for (int nt = 0; nt < 4; ++nt) {
                int n0 = bn + nw + nt * 16 + quad * 4;
                int b = n0 >> 11, s0 = n0 & 2047;
                uint2 u;
                u.x = pk2(acc[mt][nt][0] + bb, acc[mt][nt][1] + bb);
                u.y = pk2(acc[mt][nt][2] + bb, acc[mt][nt][3] + bb);
                *(uint2*)&C[((size_t)(b * NHEADS + h) * DK + d) * SEQ + s0] = u;
            }
        }
    }
}

__global__ __launch_bounds__(256) void gemm_mfma(GemmArgs g0, GemmArgs g1, GemmArgs g2)
{
    __shared__ ushort_t As[128 * 64];
    __shared__ ushort_t Bs[128 * 64];
    const int flat = blockIdx.x;          // 0..767
    const int c  = flat & 7;              // XCD
    const int rr = flat >> 3;             // 0..95
    const int t32 = c * 4 + (rr & 3);     // 0..31 (M / token tile)
    const int t8  = (rr >> 2) & 7;        // 0..7  (N / channel tile)
    const int z   = rr >> 5;              // 0..2  (matrix)
    GemmArgs ga = (z == 0) ? g0 : ((z == 1) ? g1 : g2);
    if (ga.mode == 0) gemm_core<0>(ga, t32, t8, As, Bs);
    else              gemm_core<1>(ga, t32, t8, As, Bs);
}

// ---------------------------------------------------------------------------
// O-projection GEMM (r17 structure, re-audited): 128x128 tile, EXPLICIT LDS
// double-buffer (flash-proven vmcnt(0)+barrier -> stage-other -> compute-
// current), XCD-grouped decode. Always-swapped mfma; epilogue consistent.
// out[M,N] = Hc @ Wo^T + bo, fp32 out.
// ---------------------------------------------------------------------------
__global__ __launch_bounds__(256) void gemm_o(
    const ushort_t* __restrict__ A, const ushort_t* __restrict__ W,
    const float* __restrict__ bias, float* __restrict__ C)
{
    __shared__ ushort_t As0[128 * 64], Bs0[128 * 64];
    __shared__ ushort_t As1[128 * 64], Bs1[128 * 64];   // 64KB total

    const int flat = blockIdx.x;          // 0..255
    const int c  = flat & 7;              // XCD
    const int rr = flat >> 3;             // 0..31
    const int bm = (c * 4 + (rr & 3)) * 128;   // M-tile (Hc rows, L2-hot/XCD)
    const int bn = (rr >> 2) * 128;            // N-tile

    const int tid  = threadIdx.x;
    const int w    = tid >> 6, lane = tid & 63;
    const int quad = lane >> 4, lx = lane & 15;
    const int mw = (w >> 1) * 64, nw = (w & 1) * 64;
    const int K = D_MODEL;

    f32x4 acc[4][4];
#pragma unroll
    for (int mt = 0; mt < 4; ++mt)
#pragma unroll
        for (int nt = 0; nt < 4; ++nt)
            acc[mt][nt] = (f32x4){0.f, 0.f, 0.f, 0.f};

    float4 b4[4];
#pragma unroll
    for (int nt = 0; nt < 4; ++nt)
        b4[nt] = *(const float4*)&bias[bn + nw + nt * 16 + quad * 4];

    // prologue: stage k-step 0 into buffer 0
#pragma unroll
    for (int i = 0; i < 4; ++i) {
        int r0 = (w * 4 + i) * 8;
        int rl = r0 + (lane >> 3);
        int g  = (lane & 7) ^ (rl & 7);
        gll16(&A[(size_t)(bm + rl) * K + g * 8], &As0[r0 * 64]);
        gll16(&W[(size_t)(bn + rl) * K + g * 8], &Bs0[r0 * 64]);
    }

    for (int kt = 0; kt < 16; ++kt) {
        ushort_t* Asr = (kt & 1) ? As1 : As0;
        ushort_t* Bsr = (kt & 1) ? Bs1 : Bs0;

        asm volatile("s_waitcnt vmcnt(0)" ::: "memory");
        asm volatile("s_barrier" ::: "memory");

        if (kt < 15) {
            ushort_t* Asn = (kt & 1) ? As0 : As1;
            ushort_t* Bsn = (kt & 1) ? Bs0 : Bs1;
            int k0 = (kt + 1) * 64;
#pragma unroll
            for (int i = 0; i < 4; ++i) {
                int r0 = (w * 4 + i) * 8;
                int rl = r0 + (lane >> 3);
                int g  = (lane & 7) ^ (rl & 7);
                gll16(&A[(size_t)(bm + rl) * K + k0 + g * 8], &Asn[r0 * 64]);
                gll16(&W[(size_t)(bn + rl) * K + k0 + g * 8], &Bsn[r0 * 64]);
            }
        }

#pragma unroll
        for (int ks = 0; ks < 2; ++ks) {
            short8 af[4], bf[4];
#pragma unroll
            for (int mt = 0; mt < 4; ++mt) {
                int r = mw + mt * 16 + lx;
                af[mt] = *(const short8*)&Asr[r * 64 + (((ks * 4 + quad) ^ (r & 7)) << 3)];
            }
#pragma unroll
            for (int nt = 0; nt < 4; ++nt) {
                int r = nw + nt * 16 + lx;
                bf[nt] = *(const short8*)&Bsr[r * 64 + (((ks * 4 + quad) ^ (r & 7)) << 3)];
            }
#pragma unroll
            for (int mt = 0; mt < 4; ++mt)
#pragma unroll
                for (int nt = 0; nt < 4; ++nt)
                    acc[mt][nt] = __builtin_amdgcn_mfma_f32_16x16x32_bf16(
                        bf[nt], af[mt], acc[mt][nt], 0, 0, 0);
        }
    }

    // epilogue: lane holds row m, 4 consecutive n per nt (float4 stores)
#pragma unroll
    for (int mt = 0; mt < 4; ++mt) {
        int m = bm + mw + mt * 16 + lx;
#pragma unroll
        for (int nt = 0; nt < 4; ++nt) {
            int n0 = bn + nw + nt * 16 + quad * 4;
            float4 v;
            v.x = acc[mt][nt][0] + b4[nt].x;
            v.y = acc[mt][nt][1] + b4[nt].y;
            v.z = acc[mt][nt][2] + b4[nt].z;
            v.w = acc[mt][nt][3] + b4[nt].w;
            *(float4*)&C[(size_t)m * D_MODEL + n0] = v;
        }
    }
}

// ---------------------------------------------------------------------------
// bf16 MFMA causal flash attention — EXACT r13 (best measured: 46.2µs,
// prediction-matched). Structure frozen: r12/r15 (1-wave, barrier-free)
// both regressed 2x — the 4-wave barrier structure's TLP hides K/V latency.
// ---------------------------------------------------------------------------
__device__ __forceinline__ void flash_tile(
    int qt, const size_t qbase, const size_t vbase,
    const ushort_t* __restrict__ Qp, const ushort_t* __restrict__ Kp,
    const ushort_t* __restrict__ Vt, ushort_t* __restrict__ Hc,
    ushort_t* Ks0, ushort_t* Ks1, ushort_t* Vs0, ushort_t* Vs1,
    ushort_t (*Ps)[16 * 64])
{
    const int tid  = threadIdx.x;
    const int w    = tid >> 6, lane = tid & 63;
    const int quad = lane >> 4, lx = lane & 15;

    // prologue: stage k-tile 0 into buffer 0
    {
#pragma unroll
        for (int i = 0; i < 2; ++i) {
            int r0 = (w + i * 4) * 8;
            int rl = r0 + (lane >> 3);
            int g  = (lane & 7) ^ (rl & 7);
            gll16(&Kp[qbase + (size_t)rl * D_MODEL + g * 8], &Ks0[r0 * 64]);
            gll16(&Vt[vbase + (size_t)rl * SEQ + g * 8], &Vs0[r0 * 64]);
        }
    }

    // Q fragments (row qt*64 + w*16 + lx), resident across all k-tiles
    short8 qf[2];
    {
        size_t ro = qbase + (size_t)(qt * 64 + w * 16 + lx) * D_MODEL + quad * 8;
        qf[0] = *(const short8*)&Qp[ro];
        qf[1] = *(const short8*)&Qp[ro + 32];
    }

    // per-wave P row base: pad-free 128B rows, XOR-16B swizzle on (lx&7)
    char* Pb = (char*)&Ps[w][0] + (lx << 7);
    const int hsw = (lx & 7) << 4;

    f32x4 O[4];           // O^T frags: d = nt*16+quad*4+r, q = lx
#pragma unroll
    for (int nt = 0; nt < 4; ++nt) O[nt] = (f32x4){0.f, 0.f, 0.f, 0.f};
    float mrow = -INFINITY, lrow = 0.f;   // mrow row-uniform; lrow PER-LANE partial
    const int qin = w * 16 + lx;          // q index within the 64-row tile

    for (int kt = 0; kt <= qt; ++kt) {
        ushort_t* Ks = (kt & 1) ? Ks1 : Ks0;
        ushort_t* Vs = (kt & 1) ? Vs1 : Vs0;

        // tile-kt loads were issued one full iteration ago
        asm volatile("s_waitcnt vmcnt(0)" ::: "memory");
        asm volatile("s_barrier" ::: "memory");

        // prefetch k-tile kt+1 into the other buffer (overlaps compute below)
        if (kt < qt) {
            ushort_t* Kn = (kt & 1) ? Ks0 : Ks1;
            ushort_t* Vn = (kt & 1) ? Vs0 : Vs1;
#pragma unroll
            for (int i = 0; i < 2; ++i) {
                int r0 = (w + i * 4) * 8;
                int rl = r0 + (lane >> 3);
                int g  = (lane & 7) ^ (rl & 7);
                gll16(&Kp[qbase + (size_t)((kt + 1) * 64 + rl) * D_MODEL + g * 8], &Kn[r0 * 64]);
                gll16(&Vt[vbase + (size_t)rl * SEQ + (kt + 1) * 64 + g * 8], &Vn[r0 * 64]);
            }
        }

        // S^T = K Q^T : s[nt][r] = S[q=lx][k = nt*16+quad*4+r]
        f32x4 s[4];
        __builtin_amdgcn_s_setprio(1);
#pragma unroll
        for (int nt = 0; nt < 4; ++nt) {
            int r = nt * 16 + lx;
            short8 kf0 = *(const short8*)&Ks[r * 64 + ((quad ^ (r & 7)) << 3)];
            short8 kf1 = *(const short8*)&Ks[r * 64 + (((4 + quad) ^ (r & 7)) << 3)];
            f32x4 z = (f32x4){0.f, 0.f, 0.f, 0.f};
            z = __builtin_amdgcn_mfma_f32_16x16x32_bf16(kf0, qf[0], z, 0, 0, 0);
            z = __builtin_amdgcn_mfma_f32_16x16x32_bf16(kf1, qf[1], z, 0, 0, 0);
            s[nt] = z;
        }
        __builtin_amdgcn_s_setprio(0);

        // causal mask (diagonal tile only); values already in log2 domain
        if (kt == qt) {
#pragma unroll
            for (int nt = 0; nt < 4; ++nt)
#pragma unroll
                for (int r = 0; r < 4; ++r)
                    if ((nt * 16 + quad * 4 + r) > qin) s[nt][r] = -INFINITY;
        }

        // per-lane max (tree); cross-lane reduce only if the gate fires
        float a0 = fmaxf(fmaxf(s[0][0], s[0][1]), fmaxf(s[0][2], s[0][3]));
        float a1 = fmaxf(fmaxf(s[1][0], s[1][1]), fmaxf(s[1][2], s[1][3]));
        float a2 = fmaxf(fmaxf(s[2][0], s[2][1]), fmaxf(s[2][2], s[2][3]));
        float a3 = fmaxf(fmaxf(s[3][0], s[3][1]), fmaxf(s[3][2], s[3][3]));
        float lm = fmaxf(fmaxf(a0, a1), fmaxf(a2, a3));
        if (__any(lm > mrow + 8.f)) {
            float tm = fmaxf(lm, __shfl_xor(lm, 16, 64));
            tm = fmaxf(tm, __shfl_xor(tm, 32, 64));
            float mnew = fmaxf(mrow, tm);
            float alpha = __builtin_amdgcn_exp2f(mrow - mnew);
            mrow = mnew;
            lrow *= alpha;
#pragma unroll
            for (int nt = 0; nt < 4; ++nt)
#pragma unroll
                for (int r = 0; r < 4; ++r) O[nt][r] *= alpha;
        }
#pragma unroll
        for (int nt = 0; nt < 4; ++nt)
#pragma unroll
            for (int r = 0; r < 4; ++r)
                s[nt][r] = __builtin_amdgcn_exp2f(s[nt][r] - mrow);
        // per-lane partial sum only (cross-lane reduce deferred to epilogue)
        float r0s = (s[0][0] + s[0][1]) + (s[0][2] + s[0][3]);
        float r1s = (s[1][0] + s[1][1]) + (s[1][2] + s[1][3]);
        float r2s = (s[2][0] + s[2][1]) + (s[2][2] + s[2][3]);
        float r3s = (s[3][0] + s[3][1]) + (s[3][2] + s[3][3]);
        lrow += (r0s + r1s) + (r2s + r3s);

        // P -> per-wave LDS, k-consecutive, XOR-swizzled pad-free rows
#pragma unroll
        for (int nt = 0; nt < 4; ++nt) {
            uint2 u;
            u.x = pk2(s[nt][0], s[nt][1]);
            u.y = pk2(s[nt][2], s[nt][3]);
            *(uint2*)(Pb + ((nt * 32 + quad * 8) ^ hsw)) = u;
        }

        // P A/B-frags (same-wave LDS RAW, in-order per wave)
        short8 pf0 = *(const short8*)(Pb + ((quad * 16) ^ hsw));
        short8 pf1 = *(const short8*)(Pb + ((64 + quad * 16) ^ hsw));

        // O^T += V^T-frag x P-frag
        __builtin_amdgcn_s_setprio(1);
#pragma unroll
        for (int nt = 0; nt < 4; ++nt) {
            int r = nt * 16 + lx;
            short8 vf0 = *(const short8*)&Vs[r * 64 + ((quad ^ (r & 7)) << 3)];
            short8 vf1 = *(const short8*)&Vs[r * 64 + (((4 + quad) ^ (r & 7)) << 3)];
            O[nt] = __builtin_amdgcn_mfma_f32_16x16x32_bf16(vf0, pf0, O[nt], 0, 0, 0);
            O[nt] = __builtin_amdgcn_mfma_f32_16x16x32_bf16(vf1, pf1, O[nt], 0, 0, 0);
        }
        __builtin_amdgcn_s_setprio(0);
    }

    // epilogue: finish the deferred l-reduce, then write O rows
    {
        lrow += __shfl_xor(lrow, 16, 64);
        lrow += __shfl_xor(lrow, 32, 64);
        float invl = 1.f / lrow;
        size_t ro = qbase + (size_t)(qt * 64 + w * 16 + lx) * D_MODEL;
#pragma unroll
        for (int nt = 0; nt < 4; ++nt) {
            uint2 u;
            u.x = pk2(O[nt][0] * invl, O[nt][1] * invl);
            u.y = pk2(O[nt][2] * invl, O[nt][3] * invl);
            *(uint2*)&Hc[ro + nt * 16 + quad * 4] = u;
        }
    }
}

__global__ __launch_bounds__(256) void flash_mfma(
    const ushort_t* __restrict__ Qp, const ushort_t* __restrict__ Kp,
    const ushort_t* __restrict__ Vt, ushort_t* __restrict__ Hc)
{
    __shared__ ushort_t Ks0[64 * 64], Ks1[64 * 64];
    __shared__ ushort_t Vs0[64 * 64], Vs1[64 * 64];
    __shared__ __align__(16) ushort_t Ps[4][16 * 64];   // total LDS = 40960B

    // Block swizzle: flat%8 == bh%8 -> all 32 q-tiles of a head land on one
    // XCD; per-CU slot quartet gets qt = {u, 31-u, (u+8)&31, 31-((u+8)&31)}
    // -> 66 k-iters per CU, balanced.
    const int flat = blockIdx.x;          // 0..1023
    const int c  = flat & 7;              // XCD
    const int j  = flat >> 3;             // 0..127 within XCD
    const int cu = j & 31;                // CU slot heuristic
    const int m  = j >> 5;                // 0..3 co-residency slot
    const int bh = c + (m << 3);          // head group: 4 heads per XCD
    const int u  = (cu + ((m >> 1) << 3)) & 31;
    const int qt = (m & 1) ? (NQT - 1 - u) : u;
    const int b = bh >> 4, h = bh & 15;

    const size_t qbase = (size_t)(b * SEQ) * D_MODEL + h * DK;
    const size_t vbase = (size_t)bh * DK * SEQ;

    flash_tile(qt, qbase, vbase, Qp, Kp, Vt, Hc, Ks0, Ks1, Vs0, Vs1, Ps);
}

extern "C" void kernel_launch(void* const* d_in, const int* in_sizes, int n_in,
                              void* d_out, int out_size, void* d_ws, size_t ws_size,
                              hipStream_t stream) {
    const float* inQ = (const float*)d_in[0];
    const float* inK = (const float*)d_in[1];
    const float* inV = (const float*)d_in[2];
    const float* Wq  = (const float*)d_in[3];
    const float* bq  = (const float*)d_in[4];
    const float* Wk  = (const float*)d_in[5];
    const float* bk  = (const float*)d_in[6];
    const float* Wv  = (const float*)d_in[7];
    const float* bv  = (const float*)d_in[8];
    const float* Wo  = (const float*)d_in[9];
    const float* bo  = (const float*)d_in[10];
    float* out = (float*)d_out;

    const size_t NI = (size_t)MROWS * D_MODEL;      // 4M
    const size_t NW = (size_t)D_MODEL * D_MODEL;    // 1M
    ushort_t* ws  = (ushort_t*)d_ws;
    ushort_t* Qb  = ws;                // bf16 inputs
    ushort_t* Kb  = Qb  + NI;
    ushort_t* Vb  = Kb  + NI;
    ushort_t* Wqb = Vb  + NI;          // bf16 weights
    ushort_t* Wkb = Wqb + NW;
    ushort_t* Wvb = Wkb + NW;
    ushort_t* Wob = Wvb + NW;
    ushort_t* Qp  = Wob + NW;          // projections
    ushort_t* Kp  = Qp  + NI;
    ushort_t* Vtg = Kp  + NI;          // V^T [B*H][DK][SEQ]
    ushort_t* Hc  = Vtg + NI;

    // fp32 -> bf16 (all 7 tensors, one launch)
    cvt_bf16<<<dim3(NI / 1024, 7), 256, 0, stream>>>(
        inQ, inK, inV, Wq, Wk, Wv, Wo,
        Qb, Kb, Vb, Wqb, Wkb, Wvb, Wob, (int)NI, (int)NW);

    // fused QKV projection; Q pre-scaled by 1/sqrt(dk)*log2(e).
    // V^T via transposed gemm. XCD-grouped 1-D grid (768 blocks).
    const float qsc = 0.125f * 1.44269504088896340736f;
    GemmArgs aq{Qb, Wqb, bq, (void*)Qp, 0, qsc};
    GemmArgs ak{Kb, Wkb, bk, (void*)Kp, 0, 1.0f};
    GemmArgs av{Wvb, Vb, bv, (void*)Vtg, 1, 1.0f};
    gemm_mfma<<<dim3(768), 256, 0, stream>>>(aq, ak, av);

    // attention (r13 structure: 1024 blocks, 4/CU, XCD-grouped)
    flash_mfma<<<dim3(NQT * BATCH * NHEADS), 256, 0, stream>>>(Qp, Kp, Vtg, Hc);

    // output projection: 128x128 dbuf tiles, 256 blocks, XCD-grouped
    gemm_o<<<dim3(256), 256, 0, stream>>>(Hc, Wob, bo, out);
}

// Round 10
// 207.136 us; speedup vs baseline: 1.0835x; 1.0835x over previous
//
#include <hip/hip_runtime.h>
#include <hip/hip_bf16.h>
#include <math.h>

#define D_MODEL 1024
#define NHEADS  16
#define DK      64
#define SEQ     2048
#define BATCH   2
#define MROWS   4096   // BATCH*SEQ
#define NQT     (SEQ/64)   // 32 q-tiles

typedef unsigned short ushort_t;
using short8 = __attribute__((ext_vector_type(8))) short;
using f32x4  = __attribute__((ext_vector_type(4))) float;

__device__ __forceinline__ ushort_t f2bf(float x) {
    unsigned u = __float_as_uint(x);
    u = (u + 0x7FFFu + ((u >> 16) & 1u)) >> 16;   // RNE
    return (ushort_t)u;
}

// pack 2 floats -> 2 bf16 in one uint (v_cvt_pk_bf16_f32 on gfx950)
__device__ __forceinline__ unsigned pk2(float a, float b) {
    __hip_bfloat162 h = __float22bfloat162_rn(float2{a, b});
    unsigned u;
    __builtin_memcpy(&u, &h, 4);
    return u;
}

// async global->LDS, 16B per lane; LDS dest = wave-uniform base + lane*16
__device__ __forceinline__ void gll16(const void* g, void* l) {
    __builtin_amdgcn_global_load_lds(
        (const __attribute__((address_space(1))) void*)(g),
        (__attribute__((address_space(3))) void*)(l), 16, 0, 0);
}

// ---------------------------------------------------------------------------
// fp32 -> bf16 conversion — WEIGHTS ONLY (r19: the input tensors are staged
// fp32 directly inside gemm_mfma via async gll16; their 96MB cvt round-trip
// is eliminated). 4 tensors, one launch.
// ---------------------------------------------------------------------------
__global__ __launch_bounds__(256) void cvt_bf16(
    const float* s0, const float* s1, const float* s2, const float* s3,
    ushort_t* d0, ushort_t* d1, ushort_t* d2, ushort_t* d3)
{
    const float* s; ushort_t* d;
    switch (blockIdx.y) {
        case 0: s = s0; d = d0; break;
        case 1: s = s1; d = d1; break;
        case 2: s = s2; d = d2; break;
        default: s = s3; d = d3; break;
    }
    int i = (blockIdx.x * 256 + threadIdx.x) * 4;
    float4 v = *(const float4*)&s[i];
    ushort4 o;
    o.x = f2bf(v.x); o.y = f2bf(v.y); o.z = f2bf(v.z); o.w = f2bf(v.w);
    *(ushort4*)&d[i] = o;
}

// ---------------------------------------------------------------------------
// bf16 MFMA GEMM (QKV), r19: input side staged as RAW FP32 via async gll16
// (preserves the DMA overlap r16 lost), converted fp32->bf16 in the
// fragment-read path (2x ds_read_b128 + 4x v_cvt_pk per fragment).
// Input LDS layout: 256B rows, 16B chunk c stores global chunk c ^ sr(row),
// sr(row) = ((row&7)<<1) | ((row>>3)&1)  -> per quarter-wave all 16 lanes
// hit distinct 16B slots on fragment reads = conflict-free. Weight side
// unchanged (bf16 gll16, 128B rows, (lane&7)^(row&7) source swizzle).
// LDS 48KB -> 3 blocks/CU. Grid: round-5 2-D (32,8,3) — r17's XCD grouping
// regressed (it forced 8x W streaming; reverted).
// MODE 0: C = (X @ W^T + bias)*oscale, bf16 row-major (X = inQ/inK fp32).
// MODE 1 (V^T): transposed gemm — A'=Wv (channels, bf16), B'=inV (tokens,
//   fp32); epilogue emits V^T[bh][d][s] with coalesced stores.
// mfma is ALWAYS swapped: mfma(bf, af) — lane holds A-side row (lx),
// quad*4 walks the B-side column; both epilogues assume this.
// ---------------------------------------------------------------------------
struct GemmArgs { const float* X; const ushort_t* Wb; const float* bias;
                  void* C; int mode; float oscale; };

// fp32-side fragment: rows of 64 fp32 (256B), swizzled as above.
__device__ __forceinline__ short8 xfrag(const float* Xs, int r, int j) {
    int sr = ((r & 7) << 1) | ((r >> 3) & 1);
    const char* rowp = (const char*)(Xs + r * 64);
    f32x4 lo = *(const f32x4*)(rowp + ((((2 * j)    ) ^ sr) << 4));
    f32x4 hi = *(const f32x4*)(rowp + ((((2 * j) | 1) ^ sr) << 4));
    uint4 uu;
    uu.x = pk2(lo[0], lo[1]); uu.y = pk2(lo[2], lo[3]);
    uu.z = pk2(hi[0], hi[1]); uu.w = pk2(hi[2], hi[3]);
    short8 f;
    __builtin_memcpy(&f, &uu, 16);
    return f;
}

__device__ __forceinline__ short8 wfrag(const ushort_t* Ws, int r, int j) {
    return *(const short8*)&Ws[r * 64 + ((j ^ (r & 7)) << 3)];
}

template<int MODE>
__device__ __forceinline__ void gemm_core(const GemmArgs& ga,
                                          float* Xs, ushort_t* Ws)
{
    const int tid  = threadIdx.x;
    const int w    = tid >> 6, lane = tid & 63;
    const int quad = lane >> 4, lx = lane & 15;
    const int mw = (w >> 1) * 64, nw = (w & 1) * 64;
    const int bm = (MODE == 1 ? blockIdx.y : blockIdx.x) * 128;
    const int bn = (MODE == 1 ? blockIdx.x : blockIdx.y) * 128;
    const int K = D_MODEL;
    const int xrow0 = (MODE == 0) ? bm : bn;   // fp32 input tile rows
    const int wrow0 = (MODE == 0) ? bn : bm;   // bf16 weight tile rows

    f32x4 acc[4][4];
#pragma unroll
    for (int mt = 0; mt < 4; ++mt)
#pragma unroll
        for (int nt = 0; nt < 4; ++nt)
            acc[mt][nt] = (f32x4){0.f, 0.f, 0.f, 0.f};

    float4 b4[4];
    float  bfr[4];
#pragma unroll
    for (int i = 0; i < 4; ++i) {
        if (MODE == 0) b4[i]  = *(const float4*)&ga.bias[bn + nw + i * 16 + quad * 4];
        else           bfr[i] = ga.bias[bm + mw + i * 16 + lx];   // per-row bias
    }

    for (int k0 = 0; k0 < K; k0 += 64) {
        __syncthreads();
        // weight side: bf16 async DMA (4 gll16/wave, 8 rows each)
#pragma unroll
        for (int i = 0; i < 4; ++i) {
            int r0 = (w * 4 + i) * 8;
            int rl = r0 + (lane >> 3);
            int g  = (lane & 7) ^ (rl & 7);
            gll16(&ga.Wb[(size_t)(wrow0 + rl) * K + k0 + g * 8], &Ws[r0 * 64]);
        }
        // input side: fp32 async DMA (8 gll16/wave, 4 rows each),
        // pre-swizzled global source -> linear LDS dest
#pragma unroll
        for (int i = 0; i < 8; ++i) {
            int r0 = (w * 8 + i) * 4;
            int rl = r0 + (lane >> 4);
            int cb = lane & 15;
            int sr = ((rl & 7) << 1) | ((rl >> 3) & 1);
            gll16(&ga.X[(size_t)(xrow0 + rl) * K + k0 + ((cb ^ sr) << 2)],
                  &Xs[r0 * 64]);
        }
        __syncthreads();

#pragma unroll
        for (int ks = 0; ks < 2; ++ks) {
            const int j = ks * 4 + quad;
            short8 af[4], bf[4];
#pragma unroll
            for (int mt = 0; mt < 4; ++mt) {
                int r = mw + mt * 16 + lx;
                af[mt] = (MODE == 0) ? xfrag(Xs, r, j) : wfrag(Ws, r, j);
            }
#pragma unroll
            for (int nt = 0; nt < 4; ++nt) {
                int r = nw + nt * 16 + lx;
                bf[nt] = (MODE == 0) ? wfrag(Ws, r, j) : xfrag(Xs, r, j);
            }
#pragma unroll
            for (int mt = 0; mt < 4; ++mt)
#pragma unroll
                for (int nt = 0; nt < 4; ++nt)
                    acc[mt][nt] = __builtin_amdgcn_mfma_f32_16x16x32_bf16(
                        bf[nt], af[mt], acc[mt][nt], 0, 0, 0);
        }
    }

    // epilogue (swapped-call layout): lane holds A-side row m = ..+lx,
    // 4 consecutive B-side cols per nt (quad*4).
    if (MODE == 0) {
        ushort_t* C = (ushort_t*)ga.C;
        const float os = ga.oscale;
#pragma unroll
        for (int mt = 0; mt < 4; ++mt) {
            int m = bm + mw + mt * 16 + lx;
#pragma unroll
            for (int nt = 0; nt < 4; ++nt) {
                int n0 = bn + nw + nt * 16 + quad * 4;
                uint2 u;
                u.x = pk2((acc[mt][nt][0] + b4[nt].x) * os, (acc[mt][nt][1] + b4[nt].y) * os);
                u.y = pk2((acc[mt][nt][2] + b4[nt].z) * os, (acc[mt][nt][3] + b4[nt].w) * os);
                *(uint2*)&C[(size_t)m * D_MODEL + n0] = u;
            }
        }
    } else {
        // row = channel ch (h = ch>>6, d = ch&63); col = token n0 (b, s)
        ushort_t* C = (ushort_t*)ga.C;
#pragma unroll
        for (int mt = 0; mt < 4; ++mt) {
            int ch = bm + mw + mt * 16 + lx;
            int h = ch >> 6, d = ch & 63;
            float bb = bfr[mt];
#pragma unroll
            for (int nt = 0; nt < 4; ++nt) {
                int n0 = bn + nw + nt * 16 + quad * 4;
                int b = n0 >> 11, s0 = n0 & 2047;
                uint2 u;
                u.x = pk2(acc[mt][nt][0] + bb, acc[mt][nt][1] + bb);
                u.y = pk2(acc[mt][nt][2] + bb, acc[mt][nt][3] + bb);
                *(uint2*)&C[((size_t)(b * NHEADS + h) * DK + d) * SEQ + s0] = u;
            }
        }
    }
}

__global__ __launch_bounds__(256) void gemm_mfma(GemmArgs g0, GemmArgs g1, GemmArgs g2)
{
    __shared__ float    Xs[128 * 64];   // 32KB fp32 input tile
    __shared__ ushort_t Ws[128 * 64];   // 16KB bf16 weight tile
    GemmArgs ga = (blockIdx.z == 0) ? g0 : ((blockIdx.z == 1) ? g1 : g2);
    if (ga.mode == 0) gemm_core<0>(ga, Xs, Ws);
    else              gemm_core<1>(ga, Xs, Ws);
}

// ---------------------------------------------------------------------------
// O-projection GEMM — EXACT round-5 form (in the 212.9µs best build):
// 64x128 tile (waves 2x2, each 32x64), single-buffered, 512 blocks.
// out[M,N] = Hc @ Wo^T + bo, fp32 out.
// ---------------------------------------------------------------------------
__global__ __launch_bounds__(256) void gemm_o(
    const ushort_t* __restrict__ A, const ushort_t* __restrict__ W,
    const float* __restrict__ bias, float* __restrict__ C)
{
    __shared__ ushort_t As[64 * 64];
    __shared__ ushort_t Bs[128 * 64];

    const int tid  = threadIdx.x;
    const int w    = tid >> 6, lane = tid & 63;
    const int quad = lane >> 4, lx = lane & 15;
    const int mw = (w >> 1) * 32, nw = (w & 1) * 64;
    const int bm = blockIdx.x * 64, bn = blockIdx.y * 128;
    const int K = D_MODEL;

    f32x4 acc[2][4];
#pragma unroll
    for (int mt = 0; mt < 2; ++mt)
#pragma unroll
        for (int nt = 0; nt < 4; ++nt)
            acc[mt][nt] = (f32x4){0.f, 0.f, 0.f, 0.f};

    float4 b4[4];
#pragma unroll
    for (int nt = 0; nt < 4; ++nt)
        b4[nt] = *(const float4*)&bias[bn + nw + nt * 16 + quad * 4];

    for (int k0 = 0; k0 < K; k0 += 64) {
        __syncthreads();
#pragma unroll
        for (int i = 0; i < 2; ++i) {
            int r0 = (i * 4 + w) * 8;
            int rl = r0 + (lane >> 3);
            int g  = (lane & 7) ^ (rl & 7);
            gll16(&A[(size_t)(bm + rl) * K + k0 + g * 8], &As[r0 * 64]);
        }
#pragma unroll
        for (int i = 0; i < 4; ++i) {
            int r0 = (i * 4 + w) * 8;
            int rl = r0 + (lane >> 3);
            int g  = (lane & 7) ^ (rl & 7);
            gll16(&W[(size_t)(bn + rl) * K + k0 + g * 8], &Bs[r0 * 64]);
        }
        __syncthreads();

#pragma unroll
        for (int ks = 0; ks < 2; ++ks) {
            short8 af[2], bf[4];
#pragma unroll
            for (int mt = 0; mt < 2; ++mt) {
                int r = mw + mt * 16 + lx;
                af[mt] = *(const short8*)&As[r * 64 + (((ks * 4 + quad) ^ (r & 7)) << 3)];
            }
#pragma unroll
            for (int nt = 0; nt < 4; ++nt) {
                int r = nw + nt * 16 + lx;
                bf[nt] = *(const short8*)&Bs[r * 64 + (((ks * 4 + quad) ^ (r & 7)) << 3)];
            }
#pragma unroll
            for (int mt = 0; mt < 2; ++mt)
#pragma unroll
                for (int nt = 0; nt < 4; ++nt)
                    acc[mt][nt] = __builtin_amdgcn_mfma_f32_16x16x32_bf16(
                        bf[nt], af[mt], acc[mt][nt], 0, 0, 0);
        }
    }

#pragma unroll
    for (int mt = 0; mt < 2; ++mt) {
        int m = bm + mw + mt * 16 + lx;
#pragma unroll
        for (int nt = 0; nt < 4; ++nt) {
            int n0 = bn + nw + nt * 16 + quad * 4;
            float4 v;
            v.x = acc[mt][nt][0] + b4[nt].x;
            v.y = acc[mt][nt][1] + b4[nt].y;
            v.z = acc[mt][nt][2] + b4[nt].z;
            v.w = acc[mt][nt][3] + b4[nt].w;
            *(float4*)&C[(size_t)m * D_MODEL + n0] = v;
        }
    }
}

// ---------------------------------------------------------------------------
// bf16 MFMA causal flash attention — EXACT r13 (best measured: 46.2µs,
// prediction-matched). Structure frozen: r12/r15 (1-wave, barrier-free)
// both regressed 2x — the 4-wave barrier structure's TLP hides K/V latency.
// ---------------------------------------------------------------------------
__device__ __forceinline__ void flash_tile(
    int qt, const size_t qbase, const size_t vbase,
    const ushort_t* __restrict__ Qp, const ushort_t* __restrict__ Kp,
    const ushort_t* __restrict__ Vt, ushort_t* __restrict__ Hc,
    ushort_t* Ks0, ushort_t* Ks1, ushort_t* Vs0, ushort_t* Vs1,
    ushort_t (*Ps)[16 * 64])
{
    const int tid  = threadIdx.x;
    const int w    = tid >> 6, lane = tid & 63;
    const int quad = lane >> 4, lx = lane & 15;

    // prologue: stage k-tile 0 into buffer 0
    {
#pragma unroll
        for (int i = 0; i < 2; ++i) {
            int r0 = (w + i * 4) * 8;
            int rl = r0 + (lane >> 3);
            int g  = (lane & 7) ^ (rl & 7);
            gll16(&Kp[qbase + (size_t)rl * D_MODEL + g * 8], &Ks0[r0 * 64]);
            gll16(&Vt[vbase + (size_t)rl * SEQ + g * 8], &Vs0[r0 * 64]);
        }
    }

    // Q fragments (row qt*64 + w*16 + lx), resident across all k-tiles
    short8 qf[2];
    {
        size_t ro = qbase + (size_t)(qt * 64 + w * 16 + lx) * D_MODEL + quad * 8;
        qf[0] = *(const short8*)&Qp[ro];
        qf[1] = *(const short8*)&Qp[ro + 32];
    }

    // per-wave P row base: pad-free 128B rows, XOR-16B swizzle on (lx&7)
    char* Pb = (char*)&Ps[w][0] + (lx << 7);
    const int hsw = (lx & 7) << 4;

    f32x4 O[4];           // O^T frags: d = nt*16+quad*4+r, q = lx
#pragma unroll
    for (int nt = 0; nt < 4; ++nt) O[nt] = (f32x4){0.f, 0.f, 0.f, 0.f};
    float mrow = -INFINITY, lrow = 0.f;   // mrow row-uniform; lrow PER-LANE partial
    const int qin = w * 16 + lx;          // q index within the 64-row tile

    for (int kt = 0; kt <= qt; ++kt) {
        ushort_t* Ks = (kt & 1) ? Ks1 : Ks0;
        ushort_t* Vs = (kt & 1) ? Vs1 : Vs0;

        // tile-kt loads were issued one full iteration ago
        asm volatile("s_waitcnt vmcnt(0)" ::: "memory");
        asm volatile("s_barrier" ::: "memory");

        // prefetch k-tile kt+1 into the other buffer (overlaps compute below)
        if (kt < qt) {
            ushort_t* Kn = (kt & 1) ? Ks0 : Ks1;
            ushort_t* Vn = (kt & 1) ? Vs0 : Vs1;
#pragma unroll
            for (int i = 0; i < 2; ++i) {
                int r0 = (w + i * 4) * 8;
                int rl = r0 + (lane >> 3);
                int g  = (lane & 7) ^ (rl & 7);
                gll16(&Kp[qbase + (size_t)((kt + 1) * 64 + rl) * D_MODEL + g * 8], &Kn[r0 * 64]);
                gll16(&Vt[vbase + (size_t)rl * SEQ + (kt + 1) * 64 + g * 8], &Vn[r0 * 64]);
            }
        }

        // S^T = K Q^T : s[nt][r] = S[q=lx][k = nt*16+quad*4+r]
        f32x4 s[4];
        __builtin_amdgcn_s_setprio(1);
#pragma unroll
        for (int nt = 0; nt < 4; ++nt) {
            int r = nt * 16 + lx;
            short8 kf0 = *(const short8*)&Ks[r * 64 + ((quad ^ (r & 7)) << 3)];
            short8 kf1 = *(const short8*)&Ks[r * 64 + (((4 + quad) ^ (r & 7)) << 3)];
            f32x4 z = (f32x4){0.f, 0.f, 0.f, 0.f};
            z = __builtin_amdgcn_mfma_f32_16x16x32_bf16(kf0, qf[0], z, 0, 0, 0);
            z = __builtin_amdgcn_mfma_f32_16x16x32_bf16(kf1, qf[1], z, 0, 0, 0);
            s[nt] = z;
        }
        __builtin_amdgcn_s_setprio(0);

        // causal mask (diagonal tile only); values already in log2 domain
        if (kt == qt) {
#pragma unroll
            for (int nt = 0; nt < 4; ++nt)
#pragma unroll
                for (int r = 0; r < 4; ++r)
                    if ((nt * 16 + quad * 4 + r) > qin) s[nt][r] = -INFINITY;
        }

        // per-lane max (tree); cross-lane reduce only if the gate fires
        float a0 = fmaxf(fmaxf(s[0][0], s[0][1]), fmaxf(s[0][2], s[0][3]));
        float a1 = fmaxf(fmaxf(s[1][0], s[1][1]), fmaxf(s[1][2], s[1][3]));
        float a2 = fmaxf(fmaxf(s[2][0], s[2][1]), fmaxf(s[2][2], s[2][3]));
        float a3 = fmaxf(fmaxf(s[3][0], s[3][1]), fmaxf(s[3][2], s[3][3]));
        float lm = fmaxf(fmaxf(a0, a1), fmaxf(a2, a3));
        if (__any(lm > mrow + 8.f)) {
            float tm = fmaxf(lm, __shfl_xor(lm, 16, 64));
            tm = fmaxf(tm, __shfl_xor(tm, 32, 64));
            float mnew = fmaxf(mrow, tm);
            float alpha = __builtin_amdgcn_exp2f(mrow - mnew);
            mrow = mnew;
            lrow *= alpha;
#pragma unroll
            for (int nt = 0; nt < 4; ++nt)
#pragma unroll
                for (int r = 0; r < 4; ++r) O[nt][r] *= alpha;
        }
#pragma unroll
        for (int nt = 0; nt < 4; ++nt)
#pragma unroll
            for (int r = 0; r < 4; ++r)
                s[nt][r] = __builtin_amdgcn_exp2f(s[nt][r] - mrow);
        // per-lane partial sum only (cross-lane reduce deferred to epilogue)
        float r0s = (s[0][0] + s[0][1]) + (s[0][2] + s[0][3]);
        float r1s = (s[1][0] + s[1][1]) + (s[1][2] + s[1][3]);
        float r2s = (s[2][0] + s[2][1]) + (s[2][2] + s[2][3]);
        float r3s = (s[3][0] + s[3][1]) + (s[3][2] + s[3][3]);
        lrow += (r0s + r1s) + (r2s + r3s);

        // P -> per-wave LDS, k-consecutive, XOR-swizzled pad-free rows
#pragma unroll
        for (int nt = 0; nt < 4; ++nt) {
            uint2 u;
            u.x = pk2(s[nt][0], s[nt][1]);
            u.y = pk2(s[nt][2], s[nt][3]);
            *(uint2*)(Pb + ((nt * 32 + quad * 8) ^ hsw)) = u;
        }

        // P A/B-frags (same-wave LDS RAW, in-order per wave)
        short8 pf0 = *(const short8*)(Pb + ((quad * 16) ^ hsw));
        short8 pf1 = *(const short8*)(Pb + ((64 + quad * 16) ^ hsw));

        // O^T += V^T-frag x P-frag
        __builtin_amdgcn_s_setprio(1);
#pragma unroll
        for (int nt = 0; nt < 4; ++nt) {
            int r = nt * 16 + lx;
            short8 vf0 = *(const short8*)&Vs[r * 64 + ((quad ^ (r & 7)) << 3)];
            short8 vf1 = *(const short8*)&Vs[r * 64 + (((4 + quad) ^ (r & 7)) << 3)];
            O[nt] = __builtin_amdgcn_mfma_f32_16x16x32_bf16(vf0, pf0, O[nt], 0, 0, 0);
            O[nt] = __builtin_amdgcn_mfma_f32_16x16x32_bf16(vf1, pf1, O[nt], 0, 0, 0);
        }
        __builtin_amdgcn_s_setprio(0);
    }

    // epilogue: finish the deferred l-reduce, then write O rows
    {
        lrow += __shfl_xor(lrow, 16, 64);
        lrow += __shfl_xor(lrow, 32, 64);
        float invl = 1.f / lrow;
        size_t ro = qbase + (size_t)(qt * 64 + w * 16 + lx) * D_MODEL;
#pragma unroll
        for (int nt = 0; nt < 4; ++nt) {
            uint2 u;
            u.x = pk2(O[nt][0] * invl, O[nt][1] * invl);
            u.y = pk2(O[nt][2] * invl, O[nt][3] * invl);
            *(uint2*)&Hc[ro + nt * 16 + quad * 4] = u;
        }
    }
}

__global__ __launch_bounds__(256) void flash_mfma(
    const ushort_t* __restrict__ Qp, const ushort_t* __restrict__ Kp,
    const ushort_t* __restrict__ Vt, ushort_t* __restrict__ Hc)
{
    __shared__ ushort_t Ks0[64 * 64], Ks1[64 * 64];
    __shared__ ushort_t Vs0[64 * 64], Vs1[64 * 64];
    __shared__ __align__(16) ushort_t Ps[4][16 * 64];   // total LDS = 40960B

    // Block swizzle: flat%8 == bh%8 -> all 32 q-tiles of a head land on one
    // XCD; per-CU slot quartet gets qt = {u, 31-u, (u+8)&31, 31-((u+8)&31)}
    // -> 66 k-iters per CU, balanced.
    const int flat = blockIdx.x;          // 0..1023
    const int c  = flat & 7;              // XCD
    const int j  = flat >> 3;             // 0..127 within XCD
    const int cu = j & 31;                // CU slot heuristic
    const int m  = j >> 5;                // 0..3 co-residency slot
    const int bh = c + (m << 3);          // head group: 4 heads per XCD
    const int u  = (cu + ((m >> 1) << 3)) & 31;
    const int qt = (m & 1) ? (NQT - 1 - u) : u;
    const int b = bh >> 4, h = bh & 15;

    const size_t qbase = (size_t)(b * SEQ) * D_MODEL + h * DK;
    const size_t vbase = (size_t)bh * DK * SEQ;

    flash_tile(qt, qbase, vbase, Qp, Kp, Vt, Hc, Ks0, Ks1, Vs0, Vs1, Ps);
}

extern "C" void kernel_launch(void* const* d_in, const int* in_sizes, int n_in,
                              void* d_out, int out_size, void* d_ws, size_t ws_size,
                              hipStream_t stream) {
    const float* inQ = (const float*)d_in[0];
    const float* inK = (const float*)d_in[1];
    const float* inV = (const float*)d_in[2];
    const float* Wq  = (const float*)d_in[3];
    const float* bq  = (const float*)d_in[4];
    const float* Wk  = (const float*)d_in[5];
    const float* bk  = (const float*)d_in[6];
    const float* Wv  = (const float*)d_in[7];
    const float* bv  = (const float*)d_in[8];
    const float* Wo  = (const float*)d_in[9];
    const float* bo  = (const float*)d_in[10];
    float* out = (float*)d_out;

    const size_t NI = (size_t)MROWS * D_MODEL;      // 4M
    const size_t NW = (size_t)D_MODEL * D_MODEL;    // 1M
    ushort_t* ws  = (ushort_t*)d_ws;
    ushort_t* Wqb = ws;                // bf16 weights
    ushort_t* Wkb = Wqb + NW;
    ushort_t* Wvb = Wkb + NW;
    ushort_t* Wob = Wvb + NW;
    ushort_t* Qp  = Wob + NW;          // projections
    ushort_t* Kp  = Qp  + NI;
    ushort_t* Vtg = Kp  + NI;          // V^T [B*H][DK][SEQ]
    ushort_t* Hc  = Vtg + NI;

    // fp32 -> bf16, weights only (inputs staged fp32 inside gemm_mfma)
    cvt_bf16<<<dim3(NW / 1024, 4), 256, 0, stream>>>(
        Wq, Wk, Wv, Wo, Wqb, Wkb, Wvb, Wob);

    // fused QKV projection; Q pre-scaled by 1/sqrt(dk)*log2(e).
    // Inputs read fp32 via async gll16 + fragment-path cvt; V^T transposed.
    const float qsc = 0.125f * 1.44269504088896340736f;
    GemmArgs aq{inQ, Wqb, bq, (void*)Qp, 0, qsc};
    GemmArgs ak{inK, Wkb, bk, (void*)Kp, 0, 1.0f};
    GemmArgs av{inV, Wvb, bv, (void*)Vtg, 1, 1.0f};
    gemm_mfma<<<dim3(MROWS / 128, D_MODEL / 128, 3), 256, 0, stream>>>(aq, ak, av);

    // attention (r13 structure: 1024 blocks, 4/CU, XCD-grouped)
    flash_mfma<<<dim3(NQT * BATCH * NHEADS), 256, 0, stream>>>(Qp, Kp, Vtg, Hc);

    // output projection (fp32 out), 64x128 single-buffer tiles, 512 blocks
    gemm_o<<<dim3(MROWS / 64, D_MODEL / 128), 256, 0, stream>>>(Hc, Wob, bo, out);
}